// Round 3
// baseline (3578.619 us; speedup 1.0000x reference)
//
#include <hip/hip_runtime.h>
#include <cstdint>
#include <cstddef>

#define N_NODES 50000
#define N_EDGES 800000
#define D 128
#define ND (N_NODES * D)        // 6,400,000 floats
#define ED (N_EDGES * D)        // 102,400,000 floats
#define TILE 32
#define NT_NODE ((N_NODES + TILE - 1) / TILE)   // 1563 (last tile ragged)
#define NT_EDGE (N_EDGES / TILE)                // 25000 exact

// Static LDS, 64 KB total (no dynamic shared / no hipFuncSetAttribute):
//   [0,     32768)  Wlo : 128 rows(c) x 128 bf16, 256 B/row, chunk-XOR swizzled
//   [32768, 49152)  A buf0 : hi [0,8192) + lo [8192,16384), 32 rows x 128 bf16
//   [49152, 65536)  A buf1
#define LWLO  0
#define LBUF0 32768
#define LBUF1 49152
#define SMEM_BYTES 65536

// stats layout (floats, in ws):
// [0:128) sum_x [128:256) sq_x [256:384) sum_y [384:512) sq_y
// [512:640) scale_n [640:768) shift_n [768:896) scale_e [896:1024) shift_e

typedef __attribute__((ext_vector_type(8))) short bf16x8;   // 8 bf16 = 4 VGPR
typedef __attribute__((ext_vector_type(4))) short bf16x4;   // 8 B
typedef __attribute__((ext_vector_type(4))) float f32x4;

__device__ __forceinline__ float sigmf(float x) {
    return 1.0f / (1.0f + __expf(-x));
}

// RTNE fp32 -> bf16 (high part)
__device__ __forceinline__ short bhi(float x) {
    unsigned u = __float_as_uint(x);
    unsigned r = u + 0x7FFFu + ((u >> 16) & 1u);
    return (short)(r >> 16);
}
// residual lo = RTNE_bf16(x - bf16(x)); consistent with bhi by construction
__device__ __forceinline__ short blo(float x) {
    unsigned u = __float_as_uint(x);
    unsigned r = (u + 0x7FFFu + ((u >> 16) & 1u)) & 0xFFFF0000u;
    float lo = x - __uint_as_float(r);
    unsigned u2 = __float_as_uint(lo);
    unsigned r2 = u2 + 0x7FFFu + ((u2 >> 16) & 1u);
    return (short)(r2 >> 16);
}

// ---- cooperative stagers (256 threads) ----
// Wlo: row c, 8B chunk kw -> byte off c*256 + ((kw*8) ^ ((c&7)<<4))
__device__ __forceinline__ void stage_Wlo(char* wlo, const float* __restrict__ Wg, int tid) {
    const float4* W4 = (const float4*)Wg;
#pragma unroll
    for (int i = 0; i < 16; ++i) {          // 4096 float4 / 256 threads
        int f = tid + i * 256;
        int row = f >> 5, kw = f & 31;
        float4 v = W4[f];
        bf16x4 l4;
        l4[0] = blo(v.x); l4[1] = blo(v.y); l4[2] = blo(v.z); l4[3] = blo(v.w);
        *(bf16x4*)(wlo + row * 256 + ((kw * 8) ^ ((row & 7) << 4))) = l4;
    }
}

// A tile (32 rows x 128) fp32 regs -> hi/lo LDS, same swizzle
__device__ __forceinline__ void conv_store_A(char* bufhi, char* buflo, const float4 rr[4], int tid) {
#pragma unroll
    for (int i2 = 0; i2 < 4; ++i2) {        // 1024 float4 / 256 threads
        int f = tid + i2 * 256;
        int row = f >> 5, kw = f & 31;
        float4 v = rr[i2];
        bf16x4 h4, l4;
        h4[0] = bhi(v.x); h4[1] = bhi(v.y); h4[2] = bhi(v.z); h4[3] = bhi(v.w);
        l4[0] = blo(v.x); l4[1] = blo(v.y); l4[2] = blo(v.z); l4[3] = blo(v.w);
        int off = row * 256 + ((kw * 8) ^ ((row & 7) << 4));
        *(bf16x4*)(bufhi + off) = h4;
        *(bf16x4*)(buflo + off) = l4;
    }
}

// per-lane loop-invariant W-hi fragments: whi[cs][ks] = W row c=ch*64+cs*16+l15,
// k-elems ks*32 + hi8*8 .. +7
__device__ __forceinline__ void load_whi(bf16x8 whi[4][4], const float* __restrict__ W,
                                         int ch, int l15, int hi8) {
#pragma unroll
    for (int cs = 0; cs < 4; ++cs) {
        const float* wr = W + (size_t)(ch * 64 + cs * 16 + l15) * D;
#pragma unroll
        for (int ks = 0; ks < 4; ++ks) {
            const float4* p = (const float4*)(wr + ks * 32 + hi8 * 8);
            float4 a = p[0], b = p[1];
            bf16x8 v;
            v[0] = bhi(a.x); v[1] = bhi(a.y); v[2] = bhi(a.z); v[3] = bhi(a.w);
            v[4] = bhi(b.x); v[5] = bhi(b.y); v[6] = bhi(b.z); v[7] = bhi(b.w);
            whi[cs][ks] = v;
        }
    }
}

// K-loop: acc[cs] (16c x 16row-group) += W(A) x E^T(B), split-bf16 3-MFMA.
// A-frag: lane = W[row=l15][k=hi8*8+j]; B-frag: lane = E[col-edge=l15][k=hi8*8+j].
__device__ __forceinline__ void kloop(const char* wlo, const char* bufhi, const char* buflo,
                                      const bf16x8 whi[4][4], int ch, int we, int l15, int hi8,
                                      f32x4 acc[4]) {
    const int erow = we * 16 + l15;
    const int eswz = (erow & 7) << 4;
    const char* Eh = bufhi + erow * 256;
    const char* El = buflo + erow * 256;
#pragma unroll
    for (int ks = 0; ks < 4; ++ks) {
        const int kb = ks * 64 + hi8 * 16;
        bf16x8 eh = *(const bf16x8*)(Eh + (kb ^ eswz));
        bf16x8 el = *(const bf16x8*)(El + (kb ^ eswz));
#pragma unroll
        for (int cs = 0; cs < 4; ++cs) {
            const int c = ch * 64 + cs * 16 + l15;
            bf16x8 wl = *(const bf16x8*)(wlo + c * 256 + (kb ^ ((c & 7) << 4)));
            acc[cs] = __builtin_amdgcn_mfma_f32_16x16x32_bf16(wl, eh, acc[cs], 0, 0, 0);
            acc[cs] = __builtin_amdgcn_mfma_f32_16x16x32_bf16(whi[cs][ks], el, acc[cs], 0, 0, 0);
            acc[cs] = __builtin_amdgcn_mfma_f32_16x16x32_bf16(whi[cs][ks], eh, acc[cs], 0, 0, 0);
        }
    }
}

__device__ __forceinline__ void load_tile_g(float4 rr[4], const float4* src4, int t, int tid,
                                            int nrows) {
#pragma unroll
    for (int i2 = 0; i2 < 4; ++i2) {
        int f = tid + i2 * 256;
        int row = t * TILE + (f >> 5);
        rr[i2] = (row < nrows) ? src4[(size_t)row * 32 + (f & 31)]
                               : make_float4(0.f, 0.f, 0.f, 0.f);
    }
}

__device__ __forceinline__ void load_tile_e(float4 rr[4], const float4* src4, int t, int tid) {
#pragma unroll
    for (int i2 = 0; i2 < 4; ++i2)
        rr[i2] = src4[(size_t)t * 1024 + tid + i2 * 256];
}

// ---- K1: four node projections ----
__device__ __forceinline__ void do_mat(const float* __restrict__ nf,
                                       const float* __restrict__ W,
                                       const float* __restrict__ b,
                                       float* __restrict__ O,
                                       char* smem, int tid) {
    const int lane = tid & 63, w = tid >> 6;
    const int ch = w & 1, we = w >> 1;
    const int l15 = lane & 15, hi8 = lane >> 4;

    stage_Wlo(smem + LWLO, W, tid);
    bf16x8 whi[4][4];
    load_whi(whi, W, ch, l15, hi8);
    f32x4 bias[4];
#pragma unroll
    for (int cs = 0; cs < 4; ++cs)
        bias[cs] = *(const f32x4*)(b + ch * 64 + cs * 16 + hi8 * 4);

    const float4* nf4 = (const float4*)nf;
    const int g = gridDim.x;
    int t = blockIdx.x;
    float4 rr[4];
    load_tile_g(rr, nf4, t, tid, N_NODES);
    conv_store_A(smem + LBUF0, smem + LBUF0 + 8192, rr, tid);
    int tn = t + g; if (tn >= NT_NODE) tn = NT_NODE - 1;
    load_tile_g(rr, nf4, tn, tid, N_NODES);
    __syncthreads();
    int cur = 0;
    for (; t < NT_NODE; t += g) {
        float4 rn[4];
        int tp = t + 2 * g; if (tp >= NT_NODE) tp = NT_NODE - 1;
        load_tile_g(rn, nf4, tp, tid, N_NODES);         // prefetch (in flight over MFMA)
        char* nh = smem + (cur ? LBUF0 : LBUF1);
        conv_store_A(nh, nh + 8192, rr, tid);           // stage tile t+g
        char* bh = smem + (cur ? LBUF1 : LBUF0);
        f32x4 acc[4];
#pragma unroll
        for (int cs = 0; cs < 4; ++cs) acc[cs] = bias[cs];
        kloop(smem + LWLO, bh, bh + 8192, whi, ch, we, l15, hi8, acc);
        int node = t * TILE + we * 16 + l15;
        if (node < N_NODES) {
            float* Orow = O + (size_t)node * D;
#pragma unroll
            for (int cs = 0; cs < 4; ++cs)
                *(f32x4*)(Orow + ch * 64 + cs * 16 + hi8 * 4) = acc[cs];
        }
        __syncthreads();
#pragma unroll
        for (int i2 = 0; i2 < 4; ++i2) rr[i2] = rn[i2];
        cur ^= 1;
    }
    __syncthreads();   // next matrix restages Wlo
}

extern "C" __global__ void __launch_bounds__(256, 2)
k_nodeproj(const float* __restrict__ nf,
           const float* __restrict__ W0, const float* __restrict__ b0,
           const float* __restrict__ W1, const float* __restrict__ b1,
           const float* __restrict__ W2, const float* __restrict__ b2,
           const float* __restrict__ W3, const float* __restrict__ b3,
           float* __restrict__ O0, float* __restrict__ O1,
           float* __restrict__ O2, float* __restrict__ O3) {
    __shared__ __align__(16) char smem[SMEM_BYTES];
    int tid = threadIdx.x;
    do_mat(nf, W0, b0, O0, smem, tid);
    do_mat(nf, W1, b1, O1, smem, tid);
    do_mat(nf, W2, b2, O2, smem, tid);
    do_mat(nf, W3, b3, O3, smem, tid);
}

// ---- K2: fused edge kernel ----
extern "C" __global__ void __launch_bounds__(256, 2)
k_edge(const float* __restrict__ ef, const int* __restrict__ idx,
       const float* __restrict__ Weg, const float* __restrict__ beg,
       const float* __restrict__ S, const float* __restrict__ Dg,
       const float* __restrict__ Du,
       float* __restrict__ yout, float* __restrict__ ssh, float* __restrict__ ss,
       float* __restrict__ stats) {
    __shared__ __align__(16) char smem[SMEM_BYTES];
    const int tid = threadIdx.x;
    const int lane = tid & 63, w = tid >> 6;
    const int ch = w & 1, we = w >> 1;
    const int l15 = lane & 15, hi8 = lane >> 4;
    const float4* ef4 = (const float4*)ef;
    const int* idx_i = idx;
    const int* idx_j = idx + N_EDGES;

    stage_Wlo(smem + LWLO, Weg, tid);
    bf16x8 whi[4][4];
    load_whi(whi, Weg, ch, l15, hi8);
    f32x4 bias[4];
#pragma unroll
    for (int cs = 0; cs < 4; ++cs)
        bias[cs] = *(const f32x4*)(beg + ch * 64 + cs * 16 + hi8 * 4);

    f32x4 sum_y[4], sq_y[4];
#pragma unroll
    for (int cs = 0; cs < 4; ++cs) { sum_y[cs] = 0.f; sq_y[cs] = 0.f; }

    const int g = gridDim.x;
    int t = blockIdx.x;
    float4 rr[4];
    load_tile_e(rr, ef4, t, tid);
    conv_store_A(smem + LBUF0, smem + LBUF0 + 8192, rr, tid);
    int tn = t + g; if (tn >= NT_EDGE) tn = NT_EDGE - 1;
    load_tile_e(rr, ef4, tn, tid);
    __syncthreads();
    int cur = 0;
    for (; t < NT_EDGE; t += g) {
        float4 rn[4];
        int tp = t + 2 * g; if (tp >= NT_EDGE) tp = NT_EDGE - 1;
        load_tile_e(rn, ef4, tp, tid);                  // prefetch
        char* nh = smem + (cur ? LBUF0 : LBUF1);
        conv_store_A(nh, nh + 8192, rr, tid);           // stage tile t+g
        char* bh = smem + (cur ? LBUF1 : LBUF0);
        f32x4 acc[4];
#pragma unroll
        for (int cs = 0; cs < 4; ++cs) acc[cs] = bias[cs];
        kloop(smem + LWLO, bh, bh + 8192, whi, ch, we, l15, hi8, acc);

        const int e = t * TILE + we * 16 + l15;         // this lane's edge
        const int i = idx_i[e], j = idx_j[e];
        const size_t ib = (size_t)i * D, jb = (size_t)j * D, eb = (size_t)e * D;
#pragma unroll
        for (int cs = 0; cs < 4; ++cs) {
            const int cb = ch * 64 + cs * 16 + hi8 * 4;
            float4 s  = *(const float4*)(S  + ib + cb);
            float4 dg = *(const float4*)(Dg + jb + cb);
            float4 du = *(const float4*)(Du + jb + cb);
            f32x4 y = acc[cs];
            y[0] += s.x + dg.x; y[1] += s.y + dg.y;
            y[2] += s.z + dg.z; y[3] += s.w + dg.w;
            *(f32x4*)(yout + eb + cb) = y;
            sum_y[cs] += y;
            sq_y[cs] += y * y;
            float sg0 = sigmf(y[0]), sg1 = sigmf(y[1]);
            float sg2 = sigmf(y[2]), sg3 = sigmf(y[3]);
            float* ssp = ss + ib + cb;
            float* shp = ssh + ib + cb;
            atomicAdd(ssp + 0, sg0); atomicAdd(ssp + 1, sg1);
            atomicAdd(ssp + 2, sg2); atomicAdd(ssp + 3, sg3);
            atomicAdd(shp + 0, du.x * sg0); atomicAdd(shp + 1, du.y * sg1);
            atomicAdd(shp + 2, du.z * sg2); atomicAdd(shp + 3, du.w * sg3);
        }
        __syncthreads();
#pragma unroll
        for (int i2 = 0; i2 < 4; ++i2) rr[i2] = rn[i2];
        cur ^= 1;
    }

    // block-level BN stat reduction (reuse buf0; all waves past final sync)
    float* colsum = (float*)(smem + LBUF0);
    float* colsq = colsum + 128;
    if (tid < 128) { colsum[tid] = 0.f; colsq[tid] = 0.f; }
    __syncthreads();
#pragma unroll
    for (int cs = 0; cs < 4; ++cs) {
        const int cb = ch * 64 + cs * 16 + hi8 * 4;
#pragma unroll
        for (int r = 0; r < 4; ++r) {
            atomicAdd(&colsum[cb + r], sum_y[cs][r]);
            atomicAdd(&colsq[cb + r], sq_y[cs][r]);
        }
    }
    __syncthreads();
    if (tid < 128) {
        atomicAdd(&stats[256 + tid], colsum[tid]);
        atomicAdd(&stats[384 + tid], colsq[tid]);
    }
}

// ---- K3: h = ssh/(ss+1e-6); x_pre = Su + h; node BN partial stats ----
extern "C" __global__ void __launch_bounds__(256)
k_nodeh(const float* __restrict__ ssh, const float* __restrict__ ss,
        const float* __restrict__ Su, float* __restrict__ xout,
        float* __restrict__ stats) {
    __shared__ float red[256 * 9];
    int tid = threadIdx.x;
    int gtid = blockIdx.x * 256 + tid;
    int TOT = gridDim.x * 256;
    int cg = tid & 31;
    int c0 = cg * 4;
    const float4* a4 = (const float4*)ssh;
    const float4* b4 = (const float4*)ss;
    const float4* s4 = (const float4*)Su;
    float4* x4 = (float4*)xout;

    float4 sum = make_float4(0.f, 0.f, 0.f, 0.f);
    float4 sq = make_float4(0.f, 0.f, 0.f, 0.f);
    for (int f = gtid; f < ND / 4; f += TOT) {
        float4 a = a4[f], b = b4[f], c = s4[f];
        float4 x;
        x.x = c.x + a.x / (b.x + 1e-6f);
        x.y = c.y + a.y / (b.y + 1e-6f);
        x.z = c.z + a.z / (b.z + 1e-6f);
        x.w = c.w + a.w / (b.w + 1e-6f);
        x4[f] = x;
        sum.x += x.x; sum.y += x.y; sum.z += x.z; sum.w += x.w;
        sq.x += x.x * x.x; sq.y += x.y * x.y; sq.z += x.z * x.z; sq.w += x.w * x.w;
    }
    float* mine = red + tid * 9;
    mine[0] = sum.x; mine[1] = sum.y; mine[2] = sum.z; mine[3] = sum.w;
    mine[4] = sq.x;  mine[5] = sq.y;  mine[6] = sq.z;  mine[7] = sq.w;
    __syncthreads();
    if (tid < 32) {
        float a[8] = {0, 0, 0, 0, 0, 0, 0, 0};
#pragma unroll
        for (int r = 0; r < 8; ++r) {
            float* p = red + (r * 32 + cg) * 9;
#pragma unroll
            for (int k = 0; k < 8; ++k) a[k] += p[k];
        }
#pragma unroll
        for (int k = 0; k < 4; ++k) {
            atomicAdd(&stats[0 + c0 + k], a[k]);
            atomicAdd(&stats[128 + c0 + k], a[4 + k]);
        }
    }
}

// ---- K4: finalize BN stats -> scale/shift ----
extern "C" __global__ void k_stats(const float* __restrict__ gn, const float* __restrict__ bn,
                                   const float* __restrict__ ge, const float* __restrict__ be,
                                   float* __restrict__ stats) {
    int c = threadIdx.x;
    if (c < D) {
        float mean = stats[c] * (1.0f / N_NODES);
        float var = stats[128 + c] * (1.0f / N_NODES) - mean * mean;
        float sc = gn[c] * rsqrtf(var + 1e-5f);
        stats[512 + c] = sc;
        stats[640 + c] = bn[c] - mean * sc;

        float meane = stats[256 + c] * (1.0f / N_EDGES);
        float vare = stats[384 + c] * (1.0f / N_EDGES) - meane * meane;
        float sce = ge[c] * rsqrtf(vare + 1e-5f);
        stats[768 + c] = sce;
        stats[896 + c] = be[c] - meane * sce;
    }
}

// ---- K5/K6: out = base + silu(x*scale + shift), in place on io ----
extern "C" __global__ void __launch_bounds__(256)
k_bnout(const float* __restrict__ base, float* __restrict__ io,
        const float* __restrict__ stats, int scale_off, int n4) {
    int tid = threadIdx.x;
    int gtid = blockIdx.x * 256 + tid;
    int TOT = gridDim.x * 256;
    int c0 = (tid & 31) * 4;
    float4 sc = *(const float4*)(stats + scale_off + c0);
    float4 sh = *(const float4*)(stats + scale_off + 128 + c0);
    const float4* b4 = (const float4*)base;
    float4* io4 = (float4*)io;
    for (int f = gtid; f < n4; f += TOT) {
        float4 x = io4[f];
        float4 t;
        t.x = x.x * sc.x + sh.x;
        t.y = x.y * sc.y + sh.y;
        t.z = x.z * sc.z + sh.z;
        t.w = x.w * sc.w + sh.w;
        float4 b = b4[f];
        float4 o;
        o.x = b.x + t.x * sigmf(t.x);
        o.y = b.y + t.y * sigmf(t.y);
        o.z = b.z + t.z * sigmf(t.z);
        o.w = b.w + t.w * sigmf(t.w);
        io4[f] = o;
    }
}

extern "C" void kernel_launch(void* const* d_in, const int* in_sizes, int n_in,
                              void* d_out, int out_size, void* d_ws, size_t ws_size,
                              hipStream_t stream) {
    const float* nf = (const float*)d_in[0];
    const float* ef = (const float*)d_in[1];
    const int* idx = (const int*)d_in[2];
    const float* Wsg = (const float*)d_in[3];
    const float* bsg = (const float*)d_in[4];
    const float* Wdg = (const float*)d_in[5];
    const float* bdg = (const float*)d_in[6];
    const float* Weg = (const float*)d_in[7];
    const float* beg = (const float*)d_in[8];
    const float* Wsu = (const float*)d_in[9];
    const float* bsu = (const float*)d_in[10];
    const float* Wdu = (const float*)d_in[11];
    const float* bdu = (const float*)d_in[12];
    const float* gn = (const float*)d_in[13];
    const float* btn = (const float*)d_in[14];
    const float* ge = (const float*)d_in[15];
    const float* bte = (const float*)d_in[16];

    float* ws = (float*)d_ws;
    float* S = ws;
    float* Dg = ws + (size_t)ND;
    float* Du = ws + 2 * (size_t)ND;
    float* Su = ws + 3 * (size_t)ND;
    float* ssh = ws + 4 * (size_t)ND;
    float* ssm = ws + 5 * (size_t)ND;
    float* stats = ws + 6 * (size_t)ND;

    float* xout = (float*)d_out;          // [N, D]
    float* yout = xout + (size_t)ND;      // [E, D] (pre-BN y staged, finalized in place)

    hipMemsetAsync(ssh, 0, (2 * (size_t)ND + 1024) * sizeof(float), stream);

    k_nodeproj<<<512, 256, 0, stream>>>(nf, Wsg, bsg, Wdg, bdg, Wdu, bdu, Wsu, bsu,
                                        S, Dg, Du, Su);
    k_edge<<<512, 256, 0, stream>>>(ef, idx, Weg, beg, S, Dg, Du, yout, ssh, ssm, stats);
    k_nodeh<<<512, 256, 0, stream>>>(ssh, ssm, Su, xout, stats);
    k_stats<<<1, 128, 0, stream>>>(gn, btn, ge, bte, stats);
    k_bnout<<<512, 256, 0, stream>>>(nf, xout, stats, 512, ND / 4);
    k_bnout<<<2048, 256, 0, stream>>>(ef, yout, stats, 768, ED / 4);
}

// Round 4
// 1656.173 us; speedup vs baseline: 2.1608x; 2.1608x over previous
//
#include <hip/hip_runtime.h>
#include <cstdint>
#include <cstddef>

#define N_NODES 50000
#define N_EDGES 800000
#define D 128
#define ND (N_NODES * D)        // 6,400,000 floats
#define ED (N_EDGES * D)        // 102,400,000 floats
#define TILE 32
#define NT_NODE ((N_NODES + TILE - 1) / TILE)   // 1563 (last tile ragged)
#define NT_EDGE (N_EDGES / TILE)                // 25000 exact

// Static LDS, 64 KB (GEMM kernels):
//   [0,     32768)  Wlo : 128 rows(c) x 128 bf16, 256 B/row, chunk-XOR swizzled
//   [32768, 49152)  A buf0 : hi [0,8192) + lo [8192,16384)
//   [49152, 65536)  A buf1
#define LWLO  0
#define LBUF0 32768
#define LBUF1 49152
#define SMEM_BYTES 65536

// ws layout: 4*ND floats (S, Dg, Du, Su), then int region (CSR), then stats.
// int region offsets (ints, from ibase = (int*)(ws + 4*ND)):
#define IOFF_ROWPTR 0         // 50001 ints
#define IOFF_CURSOR 65536     // 50000 ints (doubles as histogram count)
#define IOFF_PERM   131072    // 800000 ints
#define IOFF_JARR   950272    // 800000 ints
#define STATS_OFF   (4 * (size_t)ND + 2097152)   // floats
// stats (floats): [0:128) sum_x [128:256) sq_x [256:384) sum_y [384:512) sq_y
// [512:640) scale_n [640:768) shift_n [768:896) scale_e [896:1024) shift_e

typedef __attribute__((ext_vector_type(8))) short bf16x8;
typedef __attribute__((ext_vector_type(4))) short bf16x4;
typedef __attribute__((ext_vector_type(4))) float f32x4;

__device__ __forceinline__ float sigmf(float x) {
    return 1.0f / (1.0f + __expf(-x));
}

__device__ __forceinline__ short bhi(float x) {
    unsigned u = __float_as_uint(x);
    unsigned r = u + 0x7FFFu + ((u >> 16) & 1u);
    return (short)(r >> 16);
}
__device__ __forceinline__ short blo(float x) {
    unsigned u = __float_as_uint(x);
    unsigned r = (u + 0x7FFFu + ((u >> 16) & 1u)) & 0xFFFF0000u;
    float lo = x - __uint_as_float(r);
    unsigned u2 = __float_as_uint(lo);
    unsigned r2 = u2 + 0x7FFFu + ((u2 >> 16) & 1u);
    return (short)(r2 >> 16);
}

// ---- GEMM helpers (proven in round 3: MfmaUtil-light, correct) ----
__device__ __forceinline__ void stage_Wlo(char* wlo, const float* __restrict__ Wg, int tid) {
    const float4* W4 = (const float4*)Wg;
#pragma unroll
    for (int i = 0; i < 16; ++i) {
        int f = tid + i * 256;
        int row = f >> 5, kw = f & 31;
        float4 v = W4[f];
        bf16x4 l4;
        l4[0] = blo(v.x); l4[1] = blo(v.y); l4[2] = blo(v.z); l4[3] = blo(v.w);
        *(bf16x4*)(wlo + row * 256 + ((kw * 8) ^ ((row & 7) << 4))) = l4;
    }
}

__device__ __forceinline__ void conv_store_A(char* bufhi, char* buflo, const float4 rr[4], int tid) {
#pragma unroll
    for (int i2 = 0; i2 < 4; ++i2) {
        int f = tid + i2 * 256;
        int row = f >> 5, kw = f & 31;
        float4 v = rr[i2];
        bf16x4 h4, l4;
        h4[0] = bhi(v.x); h4[1] = bhi(v.y); h4[2] = bhi(v.z); h4[3] = bhi(v.w);
        l4[0] = blo(v.x); l4[1] = blo(v.y); l4[2] = blo(v.z); l4[3] = blo(v.w);
        int off = row * 256 + ((kw * 8) ^ ((row & 7) << 4));
        *(bf16x4*)(bufhi + off) = h4;
        *(bf16x4*)(buflo + off) = l4;
    }
}

__device__ __forceinline__ void load_whi(bf16x8 whi[4][4], const float* __restrict__ W,
                                         int ch, int l15, int hi8) {
#pragma unroll
    for (int cs = 0; cs < 4; ++cs) {
        const float* wr = W + (size_t)(ch * 64 + cs * 16 + l15) * D;
#pragma unroll
        for (int ks = 0; ks < 4; ++ks) {
            const float4* p = (const float4*)(wr + ks * 32 + hi8 * 8);
            float4 a = p[0], b = p[1];
            bf16x8 v;
            v[0] = bhi(a.x); v[1] = bhi(a.y); v[2] = bhi(a.z); v[3] = bhi(a.w);
            v[4] = bhi(b.x); v[5] = bhi(b.y); v[6] = bhi(b.z); v[7] = bhi(b.w);
            whi[cs][ks] = v;
        }
    }
}

__device__ __forceinline__ void kloop(const char* wlo, const char* bufhi, const char* buflo,
                                      const bf16x8 whi[4][4], int ch, int we, int l15, int hi8,
                                      f32x4 acc[4]) {
    const int erow = we * 16 + l15;
    const int eswz = (erow & 7) << 4;
    const char* Eh = bufhi + erow * 256;
    const char* El = buflo + erow * 256;
#pragma unroll
    for (int ks = 0; ks < 4; ++ks) {
        const int kb = ks * 64 + hi8 * 16;
        bf16x8 eh = *(const bf16x8*)(Eh + (kb ^ eswz));
        bf16x8 el = *(const bf16x8*)(El + (kb ^ eswz));
#pragma unroll
        for (int cs = 0; cs < 4; ++cs) {
            const int c = ch * 64 + cs * 16 + l15;
            bf16x8 wl = *(const bf16x8*)(wlo + c * 256 + (kb ^ ((c & 7) << 4)));
            acc[cs] = __builtin_amdgcn_mfma_f32_16x16x32_bf16(wl, eh, acc[cs], 0, 0, 0);
            acc[cs] = __builtin_amdgcn_mfma_f32_16x16x32_bf16(whi[cs][ks], el, acc[cs], 0, 0, 0);
            acc[cs] = __builtin_amdgcn_mfma_f32_16x16x32_bf16(whi[cs][ks], eh, acc[cs], 0, 0, 0);
        }
    }
}

__device__ __forceinline__ void load_tile_g(float4 rr[4], const float4* src4, int t, int tid,
                                            int nrows) {
#pragma unroll
    for (int i2 = 0; i2 < 4; ++i2) {
        int f = tid + i2 * 256;
        int row = t * TILE + (f >> 5);
        rr[i2] = (row < nrows) ? src4[(size_t)row * 32 + (f & 31)]
                               : make_float4(0.f, 0.f, 0.f, 0.f);
    }
}

__device__ __forceinline__ void load_tile_e(float4 rr[4], const float4* src4, int t, int tid) {
#pragma unroll
    for (int i2 = 0; i2 < 4; ++i2)
        rr[i2] = src4[(size_t)t * 1024 + tid + i2 * 256];
}

// ---- CSR build ----
extern "C" __global__ void __launch_bounds__(256)
k_hist(const int* __restrict__ idx, int* __restrict__ count) {
    int e = blockIdx.x * 256 + threadIdx.x;
    int stride = gridDim.x * 256;
    for (; e < N_EDGES; e += stride) atomicAdd(&count[idx[e]], 1);
}

// 1 block, 1024 threads. count aliases cursor: read count[b] first, then
// overwrite with base offset (same thread owns its bins -> safe).
extern "C" __global__ void __launch_bounds__(1024)
k_scan(int* __restrict__ cnt_cursor, int* __restrict__ rowptr) {
    __shared__ int s[1024];
    const int t = threadIdx.x;
    const int b0 = t * 49;
    int mysum = 0;
#pragma unroll 1
    for (int k = 0; k < 49; ++k) {
        int b = b0 + k;
        if (b < N_NODES) mysum += cnt_cursor[b];
    }
    s[t] = mysum;
    __syncthreads();
    for (int off = 1; off < 1024; off <<= 1) {
        int v = (t >= off) ? s[t - off] : 0;
        __syncthreads();
        s[t] += v;
        __syncthreads();
    }
    int base = s[t] - mysum;   // exclusive prefix of this thread's chunk
#pragma unroll 1
    for (int k = 0; k < 49; ++k) {
        int b = b0 + k;
        if (b < N_NODES) {
            int c = cnt_cursor[b];
            rowptr[b] = base;
            cnt_cursor[b] = base;   // cursor init
            base += c;
        }
    }
    if (t == 1023) rowptr[N_NODES] = s[1023];   // = N_EDGES
}

extern "C" __global__ void __launch_bounds__(256)
k_scatter(const int* __restrict__ idx, int* __restrict__ cursor,
          int* __restrict__ perm, int* __restrict__ jarr) {
    int e = blockIdx.x * 256 + threadIdx.x;
    int stride = gridDim.x * 256;
    for (; e < N_EDGES; e += stride) {
        int i = idx[e];
        int j = idx[N_EDGES + e];
        int pos = atomicAdd(&cursor[i], 1);
        perm[pos] = e;
        jarr[pos] = j;
    }
}

// ---- K1: four node projections ----
__device__ __forceinline__ void do_mat(const float* __restrict__ nf,
                                       const float* __restrict__ W,
                                       const float* __restrict__ b,
                                       float* __restrict__ O,
                                       char* smem, int tid) {
    const int lane = tid & 63, w = tid >> 6;
    const int ch = w & 1, we = w >> 1;
    const int l15 = lane & 15, hi8 = lane >> 4;

    stage_Wlo(smem + LWLO, W, tid);
    bf16x8 whi[4][4];
    load_whi(whi, W, ch, l15, hi8);
    f32x4 bias[4];
#pragma unroll
    for (int cs = 0; cs < 4; ++cs)
        bias[cs] = *(const f32x4*)(b + ch * 64 + cs * 16 + hi8 * 4);

    const float4* nf4 = (const float4*)nf;
    const int g = gridDim.x;
    int t = blockIdx.x;
    float4 rr[4];
    load_tile_g(rr, nf4, t, tid, N_NODES);
    conv_store_A(smem + LBUF0, smem + LBUF0 + 8192, rr, tid);
    int tn = t + g; if (tn >= NT_NODE) tn = NT_NODE - 1;
    load_tile_g(rr, nf4, tn, tid, N_NODES);
    __syncthreads();
    int cur = 0;
    for (; t < NT_NODE; t += g) {
        float4 rn[4];
        int tp = t + 2 * g; if (tp >= NT_NODE) tp = NT_NODE - 1;
        load_tile_g(rn, nf4, tp, tid, N_NODES);
        char* nh = smem + (cur ? LBUF0 : LBUF1);
        conv_store_A(nh, nh + 8192, rr, tid);
        char* bh = smem + (cur ? LBUF1 : LBUF0);
        f32x4 acc[4];
#pragma unroll
        for (int cs = 0; cs < 4; ++cs) acc[cs] = bias[cs];
        kloop(smem + LWLO, bh, bh + 8192, whi, ch, we, l15, hi8, acc);
        int node = t * TILE + we * 16 + l15;
        if (node < N_NODES) {
            float* Orow = O + (size_t)node * D;
#pragma unroll
            for (int cs = 0; cs < 4; ++cs)
                *(f32x4*)(Orow + ch * 64 + cs * 16 + hi8 * 4) = acc[cs];
        }
        __syncthreads();
#pragma unroll
        for (int i2 = 0; i2 < 4; ++i2) rr[i2] = rn[i2];
        cur ^= 1;
    }
    __syncthreads();
}

extern "C" __global__ void __launch_bounds__(256, 2)
k_nodeproj(const float* __restrict__ nf,
           const float* __restrict__ W0, const float* __restrict__ b0,
           const float* __restrict__ W1, const float* __restrict__ b1,
           const float* __restrict__ W2, const float* __restrict__ b2,
           const float* __restrict__ W3, const float* __restrict__ b3,
           float* __restrict__ O0, float* __restrict__ O1,
           float* __restrict__ O2, float* __restrict__ O3) {
    __shared__ __align__(16) char smem[SMEM_BYTES];
    int tid = threadIdx.x;
    do_mat(nf, W0, b0, O0, smem, tid);
    do_mat(nf, W1, b1, O1, smem, tid);
    do_mat(nf, W2, b2, O2, smem, tid);
    do_mat(nf, W3, b3, O3, smem, tid);
}

// ---- K2: edge kernel: MFMA proj + S/Dg gathers + y write + BN-y stats.
// NO per-element atomics (segment sums moved to gather-side k_node_agg).
extern "C" __global__ void __launch_bounds__(256, 2)
k_edge(const float* __restrict__ ef, const int* __restrict__ idx,
       const float* __restrict__ Weg, const float* __restrict__ beg,
       const float* __restrict__ S, const float* __restrict__ Dg,
       float* __restrict__ yout, float* __restrict__ stats) {
    __shared__ __align__(16) char smem[SMEM_BYTES];
    const int tid = threadIdx.x;
    const int lane = tid & 63, w = tid >> 6;
    const int ch = w & 1, we = w >> 1;
    const int l15 = lane & 15, hi8 = lane >> 4;
    const float4* ef4 = (const float4*)ef;
    const int* idx_i = idx;
    const int* idx_j = idx + N_EDGES;

    stage_Wlo(smem + LWLO, Weg, tid);
    bf16x8 whi[4][4];
    load_whi(whi, Weg, ch, l15, hi8);
    f32x4 bias[4];
#pragma unroll
    for (int cs = 0; cs < 4; ++cs)
        bias[cs] = *(const f32x4*)(beg + ch * 64 + cs * 16 + hi8 * 4);

    f32x4 sum_y[4], sq_y[4];
#pragma unroll
    for (int cs = 0; cs < 4; ++cs) { sum_y[cs] = 0.f; sq_y[cs] = 0.f; }

    const int g = gridDim.x;
    int t = blockIdx.x;
    float4 rr[4];
    load_tile_e(rr, ef4, t, tid);
    conv_store_A(smem + LBUF0, smem + LBUF0 + 8192, rr, tid);
    int tn = t + g; if (tn >= NT_EDGE) tn = NT_EDGE - 1;
    load_tile_e(rr, ef4, tn, tid);
    __syncthreads();
    int cur = 0;
    for (; t < NT_EDGE; t += g) {
        float4 rn[4];
        int tp = t + 2 * g; if (tp >= NT_EDGE) tp = NT_EDGE - 1;
        load_tile_e(rn, ef4, tp, tid);
        char* nh = smem + (cur ? LBUF0 : LBUF1);
        conv_store_A(nh, nh + 8192, rr, tid);
        char* bh = smem + (cur ? LBUF1 : LBUF0);
        f32x4 acc[4];
#pragma unroll
        for (int cs = 0; cs < 4; ++cs) acc[cs] = bias[cs];
        kloop(smem + LWLO, bh, bh + 8192, whi, ch, we, l15, hi8, acc);

        const int e = t * TILE + we * 16 + l15;
        const int i = idx_i[e], j = idx_j[e];
        const size_t ib = (size_t)i * D, jb = (size_t)j * D, eb = (size_t)e * D;
#pragma unroll
        for (int cs = 0; cs < 4; ++cs) {
            const int cb = ch * 64 + cs * 16 + hi8 * 4;
            float4 s  = *(const float4*)(S  + ib + cb);
            float4 dg = *(const float4*)(Dg + jb + cb);
            f32x4 y = acc[cs];
            y[0] += s.x + dg.x; y[1] += s.y + dg.y;
            y[2] += s.z + dg.z; y[3] += s.w + dg.w;
            *(f32x4*)(yout + eb + cb) = y;
            sum_y[cs] += y;
            sq_y[cs] += y * y;
        }
        __syncthreads();
#pragma unroll
        for (int i2 = 0; i2 < 4; ++i2) rr[i2] = rn[i2];
        cur ^= 1;
    }

    // block-level BN-y stat reduction
    float* colsum = (float*)(smem + LBUF0);
    float* colsq = colsum + 128;
    if (tid < 128) { colsum[tid] = 0.f; colsq[tid] = 0.f; }
    __syncthreads();
#pragma unroll
    for (int cs = 0; cs < 4; ++cs) {
        const int cb = ch * 64 + cs * 16 + hi8 * 4;
#pragma unroll
        for (int r = 0; r < 4; ++r) {
            atomicAdd(&colsum[cb + r], sum_y[cs][r]);
            atomicAdd(&colsq[cb + r], sq_y[cs][r]);
        }
    }
    __syncthreads();
    if (tid < 128) {
        atomicAdd(&stats[256 + tid], colsum[tid]);
        atomicAdd(&stats[384 + tid], colsq[tid]);
    }
}

// ---- K3: gather-side aggregation. One wave per node (grid-stride).
// h = sum(Du[j]*sigma)/sum(sigma)+eps; x_pre = Su + h; BN-x stats.
extern "C" __global__ void __launch_bounds__(256)
k_node_agg(const float* __restrict__ y, const float* __restrict__ Du,
           const float* __restrict__ Su, const int* __restrict__ rowptr,
           const int* __restrict__ perm, const int* __restrict__ jarr,
           float* __restrict__ xout, float* __restrict__ stats) {
    __shared__ float red[256 * 4];
    const int tid = threadIdx.x;
    const int lane = tid & 63, wv = tid >> 6;
    const int c = lane * 2;
    const int gw = blockIdx.x * 4 + wv;
    const int nw = gridDim.x * 4;

    float s0 = 0.f, s1 = 0.f, q0 = 0.f, q1 = 0.f;

    for (int i = gw; i < N_NODES; i += nw) {
        const int p0 = rowptr[i], p1 = rowptr[i + 1];
        float ss0 = 0.f, ss1 = 0.f, sm0 = 0.f, sm1 = 0.f;
        int p = p0;
        int e = (p < p1) ? perm[p] : 0;
        int j = (p < p1) ? jarr[p] : 0;
        while (p < p1) {
            const int ec = e, jc = j;
            const int pn = p + 1;
            if (pn < p1) { e = perm[pn]; j = jarr[pn]; }   // prefetch next hop
            float2 yv = *(const float2*)(y + (size_t)ec * D + c);
            float2 du = *(const float2*)(Du + (size_t)jc * D + c);
            float g0 = sigmf(yv.x), g1 = sigmf(yv.y);
            ss0 += g0; ss1 += g1;
            sm0 += du.x * g0; sm1 += du.y * g1;
            p = pn;
        }
        float2 su = *(const float2*)(Su + (size_t)i * D + c);
        float x0 = su.x + sm0 / (ss0 + 1e-6f);
        float x1 = su.y + sm1 / (ss1 + 1e-6f);
        *(float2*)(xout + (size_t)i * D + c) = make_float2(x0, x1);
        s0 += x0; s1 += x1; q0 += x0 * x0; q1 += x1 * x1;
    }

    float* mine = red + tid * 4;
    mine[0] = s0; mine[1] = s1; mine[2] = q0; mine[3] = q1;
    __syncthreads();
    if (tid < 64) {
        float a0 = 0.f, a1 = 0.f, b0 = 0.f, b1 = 0.f;
#pragma unroll
        for (int w = 0; w < 4; ++w) {
            const float* p = red + ((w << 6) | tid) * 4;
            a0 += p[0]; a1 += p[1]; b0 += p[2]; b1 += p[3];
        }
        atomicAdd(&stats[0 + 2 * tid], a0);
        atomicAdd(&stats[0 + 2 * tid + 1], a1);
        atomicAdd(&stats[128 + 2 * tid], b0);
        atomicAdd(&stats[128 + 2 * tid + 1], b1);
    }
}

// ---- K4: finalize BN stats -> scale/shift ----
extern "C" __global__ void k_stats(const float* __restrict__ gn, const float* __restrict__ bn,
                                   const float* __restrict__ ge, const float* __restrict__ be,
                                   float* __restrict__ stats) {
    int c = threadIdx.x;
    if (c < D) {
        float mean = stats[c] * (1.0f / N_NODES);
        float var = stats[128 + c] * (1.0f / N_NODES) - mean * mean;
        float sc = gn[c] * rsqrtf(var + 1e-5f);
        stats[512 + c] = sc;
        stats[640 + c] = bn[c] - mean * sc;

        float meane = stats[256 + c] * (1.0f / N_EDGES);
        float vare = stats[384 + c] * (1.0f / N_EDGES) - meane * meane;
        float sce = ge[c] * rsqrtf(vare + 1e-5f);
        stats[768 + c] = sce;
        stats[896 + c] = be[c] - meane * sce;
    }
}

// ---- K5/K6: out = base + silu(x*scale + shift), in place on io ----
extern "C" __global__ void __launch_bounds__(256)
k_bnout(const float* __restrict__ base, float* __restrict__ io,
        const float* __restrict__ stats, int scale_off, int n4) {
    int tid = threadIdx.x;
    int gtid = blockIdx.x * 256 + tid;
    int TOT = gridDim.x * 256;
    int c0 = (tid & 31) * 4;
    float4 sc = *(const float4*)(stats + scale_off + c0);
    float4 sh = *(const float4*)(stats + scale_off + 128 + c0);
    const float4* b4 = (const float4*)base;
    float4* io4 = (float4*)io;
    for (int f = gtid; f < n4; f += TOT) {
        float4 x = io4[f];
        float4 t;
        t.x = x.x * sc.x + sh.x;
        t.y = x.y * sc.y + sh.y;
        t.z = x.z * sc.z + sh.z;
        t.w = x.w * sc.w + sh.w;
        float4 b = b4[f];
        float4 o;
        o.x = b.x + t.x * sigmf(t.x);
        o.y = b.y + t.y * sigmf(t.y);
        o.z = b.z + t.z * sigmf(t.z);
        o.w = b.w + t.w * sigmf(t.w);
        io4[f] = o;
    }
}

extern "C" void kernel_launch(void* const* d_in, const int* in_sizes, int n_in,
                              void* d_out, int out_size, void* d_ws, size_t ws_size,
                              hipStream_t stream) {
    const float* nf = (const float*)d_in[0];
    const float* ef = (const float*)d_in[1];
    const int* idx = (const int*)d_in[2];
    const float* Wsg = (const float*)d_in[3];
    const float* bsg = (const float*)d_in[4];
    const float* Wdg = (const float*)d_in[5];
    const float* bdg = (const float*)d_in[6];
    const float* Weg = (const float*)d_in[7];
    const float* beg = (const float*)d_in[8];
    const float* Wsu = (const float*)d_in[9];
    const float* bsu = (const float*)d_in[10];
    const float* Wdu = (const float*)d_in[11];
    const float* bdu = (const float*)d_in[12];
    const float* gn = (const float*)d_in[13];
    const float* btn = (const float*)d_in[14];
    const float* ge = (const float*)d_in[15];
    const float* bte = (const float*)d_in[16];

    float* ws = (float*)d_ws;
    float* S = ws;
    float* Dg = ws + (size_t)ND;
    float* Du = ws + 2 * (size_t)ND;
    float* Su = ws + 3 * (size_t)ND;
    int* ibase = (int*)(ws + 4 * (size_t)ND);
    int* rowptr = ibase + IOFF_ROWPTR;
    int* cursor = ibase + IOFF_CURSOR;   // doubles as histogram count
    int* perm = ibase + IOFF_PERM;
    int* jarr = ibase + IOFF_JARR;
    float* stats = ws + STATS_OFF;

    float* xout = (float*)d_out;          // [N, D]
    float* yout = xout + (size_t)ND;      // [E, D] pre-BN y staged, finalized in place

    hipMemsetAsync(cursor, 0, N_NODES * sizeof(int), stream);
    hipMemsetAsync(stats, 0, 1024 * sizeof(float), stream);

    k_hist<<<1024, 256, 0, stream>>>(idx, cursor);
    k_scan<<<1, 1024, 0, stream>>>(cursor, rowptr);
    k_scatter<<<1024, 256, 0, stream>>>(idx, cursor, perm, jarr);
    k_nodeproj<<<512, 256, 0, stream>>>(nf, Wsg, bsg, Wdg, bdg, Wdu, bdu, Wsu, bsu,
                                        S, Dg, Du, Su);
    k_edge<<<512, 256, 0, stream>>>(ef, idx, Weg, beg, S, Dg, yout, stats);
    k_node_agg<<<512, 256, 0, stream>>>(yout, Du, Su, rowptr, perm, jarr, xout, stats);
    k_stats<<<1, 128, 0, stream>>>(gn, btn, ge, bte, stats);
    k_bnout<<<512, 256, 0, stream>>>(nf, xout, stats, 512, ND / 4);
    k_bnout<<<2048, 256, 0, stream>>>(ef, yout, stats, 768, ED / 4);
}

// Round 9
// 1609.306 us; speedup vs baseline: 2.2237x; 1.0291x over previous
//
#include <hip/hip_runtime.h>
#include <cstdint>
#include <cstddef>

#define N_NODES 50000
#define N_EDGES 800000
#define D 128
#define ND (N_NODES * D)        // 6,400,000 floats
#define ED (N_EDGES * D)        // 102,400,000 floats
#define TILE 32
#define NT_NODE ((N_NODES + TILE - 1) / TILE)   // 1563 (last tile ragged)
#define NT_EDGE (N_EDGES / TILE)                // 25000 exact
#define NPB 192                                  // blocks per matrix in k_nodeproj

// Static LDS, 48 KB (GEMM kernels) -> 3 blocks/CU (160/48):
//   [0,     32768)  Wlo : 128 rows(c) x 128 bf16, 256 B/row, chunk-XOR swizzled
//   [32768, 40960)  A hi : 32 rows x 128 bf16 (single-buffered)
//   [40960, 49152)  A lo
#define LWLO  0
#define LBUFA 32768
#define SMEM_BYTES 49152

// ws layout: 4*ND floats (S, Dg, Du, Su), then int region (CSR), then stats.
#define IOFF_ROWPTR 0         // 50001 ints
#define IOFF_CURSOR 65536     // 50000 ints (doubles as histogram count)
#define IOFF_PJ     131072    // 800000 int2 = 1.6M ints
#define STATS_OFF   (4 * (size_t)ND + 2097152)   // floats
// stats (floats): [0:128) sum_x [128:256) sq_x [256:384) sum_y [384:512) sq_y
// [512:640) scale_n [640:768) shift_n [768:896) scale_e [896:1024) shift_e

typedef __attribute__((ext_vector_type(8))) short bf16x8;
typedef __attribute__((ext_vector_type(4))) short bf16x4;
typedef __attribute__((ext_vector_type(4))) float f32x4;

__device__ __forceinline__ float sigmf(float x) {
    return 1.0f / (1.0f + __expf(-x));
}

__device__ __forceinline__ short bhi(float x) {
    unsigned u = __float_as_uint(x);
    unsigned r = u + 0x7FFFu + ((u >> 16) & 1u);
    return (short)(r >> 16);
}
__device__ __forceinline__ short blo(float x) {
    unsigned u = __float_as_uint(x);
    unsigned r = (u + 0x7FFFu + ((u >> 16) & 1u)) & 0xFFFF0000u;
    float lo = x - __uint_as_float(r);
    unsigned u2 = __float_as_uint(lo);
    unsigned r2 = u2 + 0x7FFFu + ((u2 >> 16) & 1u);
    return (short)(r2 >> 16);
}

// ---- cooperative stagers (256 threads) ----
__device__ __forceinline__ void stage_Wlo(char* wlo, const float* __restrict__ Wg, int tid) {
    const float4* W4 = (const float4*)Wg;
#pragma unroll
    for (int i = 0; i < 16; ++i) {          // 4096 float4 / 256 threads
        int f = tid + i * 256;
        int row = f >> 5, kw = f & 31;
        float4 v = W4[f];
        bf16x4 l4;
        l4[0] = blo(v.x); l4[1] = blo(v.y); l4[2] = blo(v.z); l4[3] = blo(v.w);
        *(bf16x4*)(wlo + row * 256 + ((kw * 8) ^ ((row & 7) << 4))) = l4;
    }
}

__device__ __forceinline__ void conv_store_A(char* bufhi, char* buflo, const float4 rr[4], int tid) {
#pragma unroll
    for (int i2 = 0; i2 < 4; ++i2) {        // 1024 float4 / 256 threads
        int f = tid + i2 * 256;
        int row = f >> 5, kw = f & 31;
        float4 v = rr[i2];
        bf16x4 h4, l4;
        h4[0] = bhi(v.x); h4[1] = bhi(v.y); h4[2] = bhi(v.z); h4[3] = bhi(v.w);
        l4[0] = blo(v.x); l4[1] = blo(v.y); l4[2] = blo(v.z); l4[3] = blo(v.w);
        int off = row * 256 + ((kw * 8) ^ ((row & 7) << 4));
        *(bf16x4*)(bufhi + off) = h4;
        *(bf16x4*)(buflo + off) = l4;
    }
}

// per-lane loop-invariant W-hi fragments (64 VGPR)
__device__ __forceinline__ void load_whi(bf16x8 whi[4][4], const float* __restrict__ W,
                                         int ch, int l15, int hi8) {
#pragma unroll
    for (int cs = 0; cs < 4; ++cs) {
        const float* wr = W + (size_t)(ch * 64 + cs * 16 + l15) * D;
#pragma unroll
        for (int ks = 0; ks < 4; ++ks) {
            const float4* p = (const float4*)(wr + ks * 32 + hi8 * 8);
            float4 a = p[0], b = p[1];
            bf16x8 v;
            v[0] = bhi(a.x); v[1] = bhi(a.y); v[2] = bhi(a.z); v[3] = bhi(a.w);
            v[4] = bhi(b.x); v[5] = bhi(b.y); v[6] = bhi(b.z); v[7] = bhi(b.w);
            whi[cs][ks] = v;
        }
    }
}

// K-loop: acc[cs] += W x E^T, split-bf16 3-MFMA. W-hi regs, W-lo + E from LDS.
__device__ __forceinline__ void kloop(const char* wlo, const char* bufhi, const char* buflo,
                                      const bf16x8 whi[4][4], int ch, int we, int l15, int hi8,
                                      f32x4 acc[4]) {
    const int erow = we * 16 + l15;
    const int eswz = (erow & 7) << 4;
    const char* Eh = bufhi + erow * 256;
    const char* El = buflo + erow * 256;
#pragma unroll
    for (int ks = 0; ks < 4; ++ks) {
        const int kb = ks * 64 + hi8 * 16;
        bf16x8 eh = *(const bf16x8*)(Eh + (kb ^ eswz));
        bf16x8 el = *(const bf16x8*)(El + (kb ^ eswz));
#pragma unroll
        for (int cs = 0; cs < 4; ++cs) {
            const int c = ch * 64 + cs * 16 + l15;
            bf16x8 wl = *(const bf16x8*)(wlo + c * 256 + (kb ^ ((c & 7) << 4)));
            acc[cs] = __builtin_amdgcn_mfma_f32_16x16x32_bf16(wl, eh, acc[cs], 0, 0, 0);
            acc[cs] = __builtin_amdgcn_mfma_f32_16x16x32_bf16(whi[cs][ks], el, acc[cs], 0, 0, 0);
            acc[cs] = __builtin_amdgcn_mfma_f32_16x16x32_bf16(whi[cs][ks], eh, acc[cs], 0, 0, 0);
        }
    }
}

__device__ __forceinline__ void load_tile_g(float4 rr[4], const float4* src4, int t, int tid,
                                            int nrows) {
#pragma unroll
    for (int i2 = 0; i2 < 4; ++i2) {
        int f = tid + i2 * 256;
        int row = t * TILE + (f >> 5);
        rr[i2] = (row < nrows) ? src4[(size_t)row * 32 + (f & 31)]
                               : make_float4(0.f, 0.f, 0.f, 0.f);
    }
}

__device__ __forceinline__ void load_tile_e(float4 rr[4], const float4* src4, int t, int tid) {
#pragma unroll
    for (int i2 = 0; i2 < 4; ++i2)
        rr[i2] = src4[(size_t)t * 1024 + tid + i2 * 256];
}

// ---- CSR build ----
extern "C" __global__ void __launch_bounds__(256)
k_hist(const int* __restrict__ idx, int* __restrict__ count) {
    int e = blockIdx.x * 256 + threadIdx.x;
    int stride = gridDim.x * 256;
    for (; e < N_EDGES; e += stride) atomicAdd(&count[idx[e]], 1);
}

extern "C" __global__ void __launch_bounds__(1024)
k_scan(int* __restrict__ cnt_cursor, int* __restrict__ rowptr) {
    __shared__ int s[1024];
    const int t = threadIdx.x;
    const int b0 = t * 49;
    int mysum = 0;
#pragma unroll 1
    for (int k = 0; k < 49; ++k) {
        int b = b0 + k;
        if (b < N_NODES) mysum += cnt_cursor[b];
    }
    s[t] = mysum;
    __syncthreads();
    for (int off = 1; off < 1024; off <<= 1) {
        int v = (t >= off) ? s[t - off] : 0;
        __syncthreads();
        s[t] += v;
        __syncthreads();
    }
    int base = s[t] - mysum;
#pragma unroll 1
    for (int k = 0; k < 49; ++k) {
        int b = b0 + k;
        if (b < N_NODES) {
            int c = cnt_cursor[b];
            rowptr[b] = base;
            cnt_cursor[b] = base;
            base += c;
        }
    }
    if (t == 1023) rowptr[N_NODES] = s[1023];
}

extern "C" __global__ void __launch_bounds__(256)
k_scatter(const int* __restrict__ idx, int* __restrict__ cursor, int2* __restrict__ pj) {
    int e = blockIdx.x * 256 + threadIdx.x;
    int stride = gridDim.x * 256;
    for (; e < N_EDGES; e += stride) {
        int i = idx[e];
        int j = idx[N_EDGES + e];
        int pos = atomicAdd(&cursor[i], 1);
        pj[pos] = make_int2(e, j);
    }
}

// ---- K1: four node projections, matrices parallel across block ranges ----
__device__ __forceinline__ void do_mat(const float* __restrict__ nf,
                                       const float* __restrict__ W,
                                       const float* __restrict__ b,
                                       float* __restrict__ O,
                                       char* smem, int tid, int t0, int stride) {
    const int lane = tid & 63, w = tid >> 6;
    const int ch = w & 1, we = w >> 1;
    const int l15 = lane & 15, hi8 = lane >> 4;

    stage_Wlo(smem + LWLO, W, tid);
    bf16x8 whi[4][4];
    load_whi(whi, W, ch, l15, hi8);
    f32x4 bias[4];
#pragma unroll
    for (int cs = 0; cs < 4; ++cs)
        bias[cs] = *(const f32x4*)(b + ch * 64 + cs * 16 + hi8 * 4);

    const float4* nf4 = (const float4*)nf;
    int t = t0;
    float4 rr[4];
    load_tile_g(rr, nf4, t, tid, N_NODES);
    for (; t < NT_NODE; t += stride) {
        conv_store_A(smem + LBUFA, smem + LBUFA + 8192, rr, tid);
        __syncthreads();                          // staging (and 1st-iter Wlo) visible
        int tn = t + stride; if (tn >= NT_NODE) tn = NT_NODE - 1;
        float4 rn[4];
        load_tile_g(rn, nf4, tn, tid, N_NODES);   // prefetch overlaps kloop+store
        f32x4 acc[4];
#pragma unroll
        for (int cs = 0; cs < 4; ++cs) acc[cs] = bias[cs];
        kloop(smem + LWLO, smem + LBUFA, smem + LBUFA + 8192, whi, ch, we, l15, hi8, acc);
        int node = t * TILE + we * 16 + l15;
        if (node < N_NODES) {
            float* Orow = O + (size_t)node * D;
#pragma unroll
            for (int cs = 0; cs < 4; ++cs)
                *(f32x4*)(Orow + ch * 64 + cs * 16 + hi8 * 4) = acc[cs];
        }
        __syncthreads();                          // reads done before next overwrite
#pragma unroll
        for (int i2 = 0; i2 < 4; ++i2) rr[i2] = rn[i2];
    }
}

extern "C" __global__ void __launch_bounds__(256, 3)
k_nodeproj(const float* __restrict__ nf,
           const float* __restrict__ W0, const float* __restrict__ b0,
           const float* __restrict__ W1, const float* __restrict__ b1,
           const float* __restrict__ W2, const float* __restrict__ b2,
           const float* __restrict__ W3, const float* __restrict__ b3,
           float* __restrict__ O0, float* __restrict__ O1,
           float* __restrict__ O2, float* __restrict__ O3) {
    __shared__ __align__(16) char smem[SMEM_BYTES];
    const float* Ws[4] = {W0, W1, W2, W3};
    const float* bs[4] = {b0, b1, b2, b3};
    float* Os[4] = {O0, O1, O2, O3};
    int m = blockIdx.x / NPB;
    int t0 = blockIdx.x % NPB;
    do_mat(nf, Ws[m], bs[m], Os[m], smem, threadIdx.x, t0, NPB);
}

// ---- K2: edge kernel: MFMA proj + S/Dg gathers + y write (no stats, no atomics) ----
extern "C" __global__ void __launch_bounds__(256, 3)
k_edge(const float* __restrict__ ef, const int* __restrict__ idx,
       const float* __restrict__ Weg, const float* __restrict__ beg,
       const float* __restrict__ S, const float* __restrict__ Dg,
       float* __restrict__ yout) {
    __shared__ __align__(16) char smem[SMEM_BYTES];
    const int tid = threadIdx.x;
    const int lane = tid & 63, w = tid >> 6;
    const int ch = w & 1, we = w >> 1;
    const int l15 = lane & 15, hi8 = lane >> 4;
    const float4* ef4 = (const float4*)ef;
    const int* idx_i = idx;
    const int* idx_j = idx + N_EDGES;

    stage_Wlo(smem + LWLO, Weg, tid);
    bf16x8 whi[4][4];
    load_whi(whi, Weg, ch, l15, hi8);
    f32x4 bias[4];
#pragma unroll
    for (int cs = 0; cs < 4; ++cs)
        bias[cs] = *(const f32x4*)(beg + ch * 64 + cs * 16 + hi8 * 4);

    const int g = gridDim.x;
    int t = blockIdx.x;
    float4 rr[4];
    load_tile_e(rr, ef4, t, tid);
    for (; t < NT_EDGE; t += g) {
        conv_store_A(smem + LBUFA, smem + LBUFA + 8192, rr, tid);
        __syncthreads();
        int tn = t + g; if (tn >= NT_EDGE) tn = NT_EDGE - 1;
        float4 rn[4];
        load_tile_e(rn, ef4, tn, tid);            // prefetch overlaps kloop+epilogue
        f32x4 acc[4];
#pragma unroll
        for (int cs = 0; cs < 4; ++cs) acc[cs] = bias[cs];
        kloop(smem + LWLO, smem + LBUFA, smem + LBUFA + 8192, whi, ch, we, l15, hi8, acc);

        const int e = t * TILE + we * 16 + l15;   // this lane's edge
        const int i = idx_i[e], j = idx_j[e];
        const size_t ib = (size_t)i * D, jb = (size_t)j * D, eb = (size_t)e * D;
#pragma unroll
        for (int cs = 0; cs < 4; ++cs) {
            const int cb = ch * 64 + cs * 16 + hi8 * 4;
            float4 s  = *(const float4*)(S  + ib + cb);
            float4 dg = *(const float4*)(Dg + jb + cb);
            f32x4 y = acc[cs];
            y[0] += s.x + dg.x; y[1] += s.y + dg.y;
            y[2] += s.z + dg.z; y[3] += s.w + dg.w;
            *(f32x4*)(yout + eb + cb) = y;
        }
        __syncthreads();
#pragma unroll
        for (int i2 = 0; i2 < 4; ++i2) rr[i2] = rn[i2];
    }
}

// ---- K3: gather-side aggregation + BN-x AND BN-y stats. One wave per node. ----
extern "C" __global__ void __launch_bounds__(256)
k_node_agg(const float* __restrict__ y, const float* __restrict__ Du,
           const float* __restrict__ Su, const int* __restrict__ rowptr,
           const int2* __restrict__ pj,
           float* __restrict__ xout, float* __restrict__ stats) {
    __shared__ float red[256 * 8];
    const int tid = threadIdx.x;
    const int lane = tid & 63, wv = tid >> 6;
    const int c = lane * 2;
    const int gw = blockIdx.x * 4 + wv;
    const int nw = gridDim.x * 4;

    float xs0 = 0.f, xs1 = 0.f, xq0 = 0.f, xq1 = 0.f;
    float ys0 = 0.f, ys1 = 0.f, yq0 = 0.f, yq1 = 0.f;

    for (int i = gw; i < N_NODES; i += nw) {
        const int p0 = rowptr[i], p1 = rowptr[i + 1];
        const int n = p1 - p0;
        float ss0 = 0.f, ss1 = 0.f, sm0 = 0.f, sm1 = 0.f;
        float2 ya, da, yb, db;
        if (n > 0) {
            int2 ej = pj[p0];
            ya = *(const float2*)(y + (size_t)ej.x * D + c);
            da = *(const float2*)(Du + (size_t)ej.y * D + c);
        }
        if (n > 1) {
            int2 ej = pj[p0 + 1];
            yb = *(const float2*)(y + (size_t)ej.x * D + c);
            db = *(const float2*)(Du + (size_t)ej.y * D + c);
        }
        for (int k = 0; k < n; ++k) {             // depth-2 software pipeline
            const float2 yc = ya, dc = da;
            ya = yb; da = db;
            if (k + 2 < n) {                      // wave-uniform branch
                int2 ej = pj[p0 + k + 2];
                yb = *(const float2*)(y + (size_t)ej.x * D + c);
                db = *(const float2*)(Du + (size_t)ej.y * D + c);
            }
            float g0 = sigmf(yc.x), g1 = sigmf(yc.y);
            ss0 += g0; ss1 += g1;
            sm0 += dc.x * g0; sm1 += dc.y * g1;
            ys0 += yc.x; ys1 += yc.y;
            yq0 += yc.x * yc.x; yq1 += yc.y * yc.y;
        }
        float2 su = *(const float2*)(Su + (size_t)i * D + c);
        float x0 = su.x + sm0 / (ss0 + 1e-6f);
        float x1 = su.y + sm1 / (ss1 + 1e-6f);
        *(float2*)(xout + (size_t)i * D + c) = make_float2(x0, x1);
        xs0 += x0; xs1 += x1; xq0 += x0 * x0; xq1 += x1 * x1;
    }

    float* mine = red + tid * 8;
    mine[0] = xs0; mine[1] = xs1; mine[2] = xq0; mine[3] = xq1;
    mine[4] = ys0; mine[5] = ys1; mine[6] = yq0; mine[7] = yq1;
    __syncthreads();
    if (tid < 64) {
        float a[8] = {0, 0, 0, 0, 0, 0, 0, 0};
#pragma unroll
        for (int w = 0; w < 4; ++w) {
            const float* p = red + ((w << 6) | tid) * 8;
#pragma unroll
            for (int k = 0; k < 8; ++k) a[k] += p[k];
        }
        atomicAdd(&stats[0 + 2 * tid], a[0]);
        atomicAdd(&stats[0 + 2 * tid + 1], a[1]);
        atomicAdd(&stats[128 + 2 * tid], a[2]);
        atomicAdd(&stats[128 + 2 * tid + 1], a[3]);
        atomicAdd(&stats[256 + 2 * tid], a[4]);
        atomicAdd(&stats[256 + 2 * tid + 1], a[5]);
        atomicAdd(&stats[384 + 2 * tid], a[6]);
        atomicAdd(&stats[384 + 2 * tid + 1], a[7]);
    }
}

// ---- K4: finalize BN stats -> scale/shift ----
extern "C" __global__ void k_stats(const float* __restrict__ gn, const float* __restrict__ bn,
                                   const float* __restrict__ ge, const float* __restrict__ be,
                                   float* __restrict__ stats) {
    int c = threadIdx.x;
    if (c < D) {
        float mean = stats[c] * (1.0f / N_NODES);
        float var = stats[128 + c] * (1.0f / N_NODES) - mean * mean;
        float sc = gn[c] * rsqrtf(var + 1e-5f);
        stats[512 + c] = sc;
        stats[640 + c] = bn[c] - mean * sc;

        float meane = stats[256 + c] * (1.0f / N_EDGES);
        float vare = stats[384 + c] * (1.0f / N_EDGES) - meane * meane;
        float sce = ge[c] * rsqrtf(vare + 1e-5f);
        stats[768 + c] = sce;
        stats[896 + c] = be[c] - meane * sce;
    }
}

// ---- K5/K6: out = base + silu(x*scale + shift), in place on io ----
extern "C" __global__ void __launch_bounds__(256)
k_bnout(const float* __restrict__ base, float* __restrict__ io,
        const float* __restrict__ stats, int scale_off, int n4) {
    int tid = threadIdx.x;
    int gtid = blockIdx.x * 256 + tid;
    int TOT = gridDim.x * 256;
    int c0 = (tid & 31) * 4;
    float4 sc = *(const float4*)(stats + scale_off + c0);
    float4 sh = *(const float4*)(stats + scale_off + 128 + c0);
    const float4* b4 = (const float4*)base;
    float4* io4 = (float4*)io;
    for (int f = gtid; f < n4; f += TOT) {
        float4 x = io4[f];
        float4 t;
        t.x = x.x * sc.x + sh.x;
        t.y = x.y * sc.y + sh.y;
        t.z = x.z * sc.z + sh.z;
        t.w = x.w * sc.w + sh.w;
        float4 b = b4[f];
        float4 o;
        o.x = b.x + t.x * sigmf(t.x);
        o.y = b.y + t.y * sigmf(t.y);
        o.z = b.z + t.z * sigmf(t.z);
        o.w = b.w + t.w * sigmf(t.w);
        io4[f] = o;
    }
}

extern "C" void kernel_launch(void* const* d_in, const int* in_sizes, int n_in,
                              void* d_out, int out_size, void* d_ws, size_t ws_size,
                              hipStream_t stream) {
    const float* nf = (const float*)d_in[0];
    const float* ef = (const float*)d_in[1];
    const int* idx = (const int*)d_in[2];
    const float* Wsg = (const float*)d_in[3];
    const float* bsg = (const float*)d_in[4];
    const float* Wdg = (const float*)d_in[5];
    const float* bdg = (const float*)d_in[6];
    const float* Weg = (const float*)d_in[7];
    const float* beg = (const float*)d_in[8];
    const float* Wsu = (const float*)d_in[9];
    const float* bsu = (const float*)d_in[10];
    const float* Wdu = (const float*)d_in[11];
    const float* bdu = (const float*)d_in[12];
    const float* gn = (const float*)d_in[13];
    const float* btn = (const float*)d_in[14];
    const float* ge = (const float*)d_in[15];
    const float* bte = (const float*)d_in[16];

    float* ws = (float*)d_ws;
    float* S = ws;
    float* Dg = ws + (size_t)ND;
    float* Du = ws + 2 * (size_t)ND;
    float* Su = ws + 3 * (size_t)ND;
    int* ibase = (int*)(ws + 4 * (size_t)ND);
    int* rowptr = ibase + IOFF_ROWPTR;
    int* cursor = ibase + IOFF_CURSOR;   // doubles as histogram count
    int2* pj = (int2*)(ibase + IOFF_PJ);
    float* stats = ws + STATS_OFF;

    float* xout = (float*)d_out;          // [N, D]
    float* yout = xout + (size_t)ND;      // [E, D] pre-BN y staged, finalized in place

    hipMemsetAsync(cursor, 0, N_NODES * sizeof(int), stream);
    hipMemsetAsync(stats, 0, 1024 * sizeof(float), stream);

    k_hist<<<1024, 256, 0, stream>>>(idx, cursor);
    k_scan<<<1, 1024, 0, stream>>>(cursor, rowptr);
    k_scatter<<<1024, 256, 0, stream>>>(idx, cursor, pj);
    k_nodeproj<<<4 * NPB, 256, 0, stream>>>(nf, Wsg, bsg, Wdg, bdg, Wdu, bdu, Wsu, bsu,
                                            S, Dg, Du, Su);
    k_edge<<<768, 256, 0, stream>>>(ef, idx, Weg, beg, S, Dg, yout);
    k_node_agg<<<1024, 256, 0, stream>>>(yout, Du, Su, rowptr, pj, xout, stats);
    k_stats<<<1, 128, 0, stream>>>(gn, btn, ge, bte, stats);
    k_bnout<<<1024, 256, 0, stream>>>(nf, xout, stats, 512, ND / 4);
    k_bnout<<<4096, 256, 0, stream>>>(ef, yout, stats, 768, ED / 4);
}